// Round 4
// baseline (6090.667 us; speedup 1.0000x reference)
//
#include <hip/hip_runtime.h>

#define BB 64
#define TT 2048
#define FF 15
#define UU 256
#define N3 768
#define NP 128          // 128 k-pairs (256 rows) of U per column, in VGPRs as v2f16

typedef _Float16 half2v __attribute__((ext_vector_type(2)));

__device__ float  g_seq1[BB * TT * UU];          // 134 MB
__device__ float  g_xp[(size_t)BB * TT * N3];    // 402 MB (xp1 then xp2)
__device__ half2v g_U1h[NP * N3];
__device__ half2v g_U2h[NP * N3];

__device__ __forceinline__ float dot2f(half2v a, half2v b, float c) {
#if __has_builtin(__builtin_amdgcn_fdot2)
    return __builtin_amdgcn_fdot2(a, b, c, false);
#else
    return c + (float)a.x * (float)b.x + (float)a.y * (float)b.y;
#endif
}

// Pack U (fp32 [256][768]) into k-pair f16 layout: Uh[p*768+j] = {U[2p][j], U[2p+1][j]}
__global__ __launch_bounds__(256) void prep_uh(const float* __restrict__ U,
                                               half2v* __restrict__ Uh) {
    int idx = blockIdx.x * 256 + threadIdx.x;
    int p = idx / N3, j = idx - p * N3;
    half2v v;
    v.x = (_Float16)U[(2 * p + 0) * N3 + j];
    v.y = (_Float16)U[(2 * p + 1) * N3 + j];
    Uh[idx] = v;
}

// xp1 = x @ W1 + b_in   (K=15, memory-bound)
__global__ __launch_bounds__(256) void gemm_k15(
    const float* __restrict__ x, const float* __restrict__ W1,
    const float* __restrict__ bin, float* __restrict__ C) {
    __shared__ float xr[8][FF];
    const int m0 = blockIdx.x * 8;
    const int j  = blockIdx.y * 256 + threadIdx.x;
    if (threadIdx.x < 8 * FF) {
        int r = threadIdx.x / FF, k = threadIdx.x - r * FF;
        xr[r][k] = x[(size_t)(m0 + r) * FF + k];
    }
    __syncthreads();
    float wv[FF];
#pragma unroll
    for (int k = 0; k < FF; k++) wv[k] = W1[k * N3 + j];
    const float bj = bin[j];
#pragma unroll
    for (int r = 0; r < 8; r++) {
        float a = bj;
#pragma unroll
        for (int k = 0; k < FF; k++) a += xr[r][k] * wv[k];
        C[(size_t)(m0 + r) * N3 + j] = a;
    }
}

// xp2 = seq1 @ W2 + b_in   (M=131072, N=768, K=256) tiled fp32 GEMM
__global__ __launch_bounds__(256) void gemm_xp(
    const float* __restrict__ A, const float* __restrict__ Bw,
    const float* __restrict__ bin, float* __restrict__ C) {
    __shared__ float As[16][64];
    __shared__ float Bs[16][64];
    const int tid = threadIdx.x;
    const int m0 = blockIdx.x * 64, n0 = blockIdx.y * 64;
    const int tm = (tid & 15) * 4;
    const int tn = (tid >> 4) * 4;
    float acc[4][4] = {};
    const int lm = tid >> 2, lk = (tid & 3) * 4;
    const int lkb = tid >> 4, ln = (tid & 15) * 4;
    for (int k0 = 0; k0 < 256; k0 += 16) {
        float4 av = *(const float4*)&A[(size_t)(m0 + lm) * 256 + k0 + lk];
        float4 bv = *(const float4*)&Bw[(size_t)(k0 + lkb) * N3 + n0 + ln];
        As[lk + 0][lm] = av.x; As[lk + 1][lm] = av.y;
        As[lk + 2][lm] = av.z; As[lk + 3][lm] = av.w;
        *(float4*)&Bs[lkb][ln] = bv;
        __syncthreads();
#pragma unroll
        for (int kk = 0; kk < 16; kk++) {
            float4 a = *(const float4*)&As[kk][tm];
            float4 b = *(const float4*)&Bs[kk][tn];
            acc[0][0] += a.x * b.x; acc[0][1] += a.x * b.y; acc[0][2] += a.x * b.z; acc[0][3] += a.x * b.w;
            acc[1][0] += a.y * b.x; acc[1][1] += a.y * b.y; acc[1][2] += a.y * b.z; acc[1][3] += a.y * b.w;
            acc[2][0] += a.z * b.x; acc[2][1] += a.z * b.y; acc[2][2] += a.z * b.z; acc[2][3] += a.z * b.w;
            acc[3][0] += a.w * b.x; acc[3][1] += a.w * b.y; acc[3][2] += a.w * b.z; acc[3][3] += a.w * b.w;
        }
        __syncthreads();
    }
#pragma unroll
    for (int i = 0; i < 4; i++) {
        float4 o = make_float4(acc[i][0] + bin[n0 + tn + 0], acc[i][1] + bin[n0 + tn + 1],
                               acc[i][2] + bin[n0 + tn + 2], acc[i][3] + bin[n0 + tn + 3]);
        *(float4*)&C[(size_t)(m0 + tm + i) * N3 + n0 + tn] = o;
    }
}

// GRU recurrence, one WG per batch element. Thread j owns column j of U in
// 128 v2f16 VGPRs, pinned against rematerialization with an opaque asm
// constraint (round-3 showed VGPR_Count=84: LLVM re-loaded U from L2 every
// step without the pin). h broadcast from LDS as packed f16; fp32 gate math.
__global__ __launch_bounds__(768, 3) void gru_recur(
    const half2v* __restrict__ Uh, const float* __restrict__ brec,
    const float* __restrict__ xp, float* __restrict__ seq_out,
    float* __restrict__ state_out, float* __restrict__ extra_out) {
    const int b = blockIdx.x, j = threadIdx.x;

    __shared__ __align__(16) half2v h2s[NP];   // packed h (f16 pairs)
    __shared__ float h32[UU];                  // fp32 h state
    __shared__ float pre[N3];                  // z/r: xp+rec pre-summed; hh: rec only
    __shared__ float xq[UU];                   // xp3 for hh combine

    half2v ureg[NP];
#pragma unroll
    for (int p = 0; p < NP; p++) {
        ureg[p] = Uh[p * N3 + j];
        asm volatile("" : "+v"(ureg[p]));      // pin: block load-remat/sink
    }
    const float brj = brec[j];

    if (j < NP) { half2v z0; z0.x = (_Float16)0.f; z0.y = (_Float16)0.f; h2s[j] = z0; }
    if (j < UU) h32[j] = 0.f;
    __syncthreads();

    const float* __restrict__ xpb = xp + (size_t)b * TT * N3;
    float xv_cur = xpb[j];

    for (int t = 0; t < TT; t++) {
        float xv_next = (t + 1 < TT) ? xpb[(size_t)(t + 1) * N3 + j] : 0.f;

        float a0 = 0.f, a1 = 0.f, a2 = 0.f, a3 = 0.f;
        const float4* h2f4 = (const float4*)h2s;
#pragma unroll
        for (int p4 = 0; p4 < NP / 4; p4++) {
            float4 hv = h2f4[p4];
            half2v* hp = (half2v*)&hv;
            a0 = dot2f(hp[0], ureg[4 * p4 + 0], a0);
            a1 = dot2f(hp[1], ureg[4 * p4 + 1], a1);
            a2 = dot2f(hp[2], ureg[4 * p4 + 2], a2);
            a3 = dot2f(hp[3], ureg[4 * p4 + 3], a3);
        }
        float acc = (a0 + a1) + (a2 + a3) + brj;

        if (j < 2 * UU) pre[j] = acc + xv_cur;       // wave-uniform branch
        else { pre[j] = acc; xq[j - 2 * UU] = xv_cur; }
        __syncthreads();                             // S1

        if (j < UU) {
            float z  = 1.f / (1.f + __expf(-pre[j]));
            float r  = 1.f / (1.f + __expf(-pre[UU + j]));
            float hh = xq[j] + r * pre[2 * UU + j];
            hh = hh > 0.f ? hh : 0.f;
            float hn = z * h32[j] + (1.f - z) * hh;
            h32[j] = hn;
            float hp = __shfl_xor(hn, 1);
            if ((j & 1) == 0) {
                half2v pk; pk.x = (_Float16)hn; pk.y = (_Float16)hp;
                h2s[j >> 1] = pk;
            }
            if (seq_out) seq_out[(size_t)b * TT * UU + (size_t)t * UU + j] = hn;
        }
        __syncthreads();                             // S2
        xv_cur = xv_next;
    }

    if (j < UU) {
        float hn = h32[j];
        state_out[b * UU + j] = hn;
        if (extra_out) extra_out[b * UU + j] = hn;
    }
}

extern "C" void kernel_launch(void* const* d_in, const int* in_sizes, int n_in,
                              void* d_out, int out_size, void* d_ws, size_t ws_size,
                              hipStream_t stream) {
    const float* x  = (const float*)d_in[0];
    const float* W1 = (const float*)d_in[1];
    const float* U1 = (const float*)d_in[2];
    const float* b1 = (const float*)d_in[3];
    const float* W2 = (const float*)d_in[4];
    const float* U2 = (const float*)d_in[5];
    const float* b2 = (const float*)d_in[6];
    float* out = (float*)d_out;

    half2v* U1h; hipGetSymbolAddress((void**)&U1h, HIP_SYMBOL(g_U1h));
    half2v* U2h; hipGetSymbolAddress((void**)&U2h, HIP_SYMBOL(g_U2h));
    float*  seq1; hipGetSymbolAddress((void**)&seq1, HIP_SYMBOL(g_seq1));
    float*  xp;   hipGetSymbolAddress((void**)&xp,   HIP_SYMBOL(g_xp));

    prep_uh<<<NP * N3 / 256, 256, 0, stream>>>(U1, U1h);
    prep_uh<<<NP * N3 / 256, 256, 0, stream>>>(U2, U2h);

    // layer 1
    gemm_k15<<<dim3(BB * TT / 8, 3), 256, 0, stream>>>(x, W1, b1, xp);
    gru_recur<<<BB, 768, 0, stream>>>(U1h, b1 + N3, xp, seq1, out + BB * UU, nullptr);

    // layer 2
    gemm_xp<<<dim3(BB * TT / 64, N3 / 64), 256, 0, stream>>>(seq1, W2, b2, xp);
    gru_recur<<<BB, 768, 0, stream>>>(U2h, b2 + N3, xp, nullptr, out + 2 * BB * UU, out);
}